// Round 1
// baseline (1595.180 us; speedup 1.0000x reference)
//
#include <hip/hip_runtime.h>

// ---------------- problem constants ----------------
constexpr int BATCH = 16;
constexpr int TSEQ  = 32;
constexpr int BT    = BATCH * TSEQ;      // 512
constexpr int HID   = 768;
constexpr int EMB   = 768;
constexpr int TWOE  = 1536;
constexpr int G4    = 3072;              // 4*H
constexpr int KREG  = 49;
constexpr int NVOC  = 50257;
constexpr int NB_LSTM = 48;

typedef __bf16 bf16x8 __attribute__((ext_vector_type(8)));
typedef __bf16 bf16x4 __attribute__((ext_vector_type(4)));
typedef float  floatx4 __attribute__((ext_vector_type(4)));

__device__ __forceinline__ float sigm_f(float x) { return 1.f / (1.f + __expf(-x)); }
__device__ __forceinline__ float tanh_f(float x) {
    float e = __expf(2.f * x);
    return 1.f - 2.f / (e + 1.f);     // stable for +/- inf
}
__device__ __forceinline__ bf16x8 zero8() {
    bf16x8 v;
#pragma unroll
    for (int i = 0; i < 8; i++) v[i] = (__bf16)0.f;
    return v;
}

// ---------------- grid spin-barrier (all blocks resident) ----------------
__device__ __forceinline__ void grid_barrier(unsigned* bar, int slot, unsigned nblk) {
    __threadfence();
    __syncthreads();
    if (threadIdx.x == 0) {
        __hip_atomic_fetch_add(&bar[slot], 1u, __ATOMIC_ACQ_REL, __HIP_MEMORY_SCOPE_AGENT);
        while (__hip_atomic_load(&bar[slot], __ATOMIC_ACQUIRE, __HIP_MEMORY_SCOPE_AGENT) < nblk) {
            __builtin_amdgcn_s_sleep(1);
        }
    }
    __syncthreads();
    __threadfence();
}

// ---------------- init: x_b16 build, V_b16, vg_b16, zero barrier ----------------
__global__ __launch_bounds__(256) void k_init(const int* __restrict__ cap,
                                              const float* __restrict__ embW,
                                              const float* __restrict__ vg,
                                              const float* __restrict__ Vin,
                                              __bf16* __restrict__ x16,
                                              __bf16* __restrict__ V16,
                                              __bf16* __restrict__ vg16,
                                              unsigned* __restrict__ bar) {
    const int NX = BT * TWOE;            // 786432
    const int NV = BATCH * KREG * EMB;   // 602112
    const int NG = BATCH * HID;          // 12288
    int i = blockIdx.x * 256 + threadIdx.x;
    if (i < NX) {
        int bt = i / TWOE, d = i - bt * TWOE;
        float v;
        if (d < EMB) {
            int tok = cap[bt];
            v = embW[(size_t)tok * EMB + d];
        } else {
            int b = bt >> 5;
            v = vg[b * EMB + (d - EMB)];
        }
        x16[i] = (__bf16)v;
    } else if (i < NX + NV) {
        int j = i - NX;
        V16[j] = (__bf16)Vin[j];
    } else if (i < NX + NV + NG) {
        int j = i - NX - NV;
        vg16[j] = (__bf16)vg[j];
    } else if (i < NX + NV + NG + 64) {
        bar[i - NX - NV - NG] = 0u;
    }
}

// ---------------- xmean (mean over t of x) in bf16 ----------------
__global__ __launch_bounds__(256) void k_xmean(const int* __restrict__ cap,
                                               const float* __restrict__ embW,
                                               const float* __restrict__ vg,
                                               __bf16* __restrict__ xm16) {
    int i = blockIdx.x * 256 + threadIdx.x;
    if (i >= BATCH * TWOE) return;
    int b = i / TWOE, d = i - b * TWOE;
    float v;
    if (d < EMB) {
        float s = 0.f;
        for (int t = 0; t < TSEQ; t++) s += embW[(size_t)cap[b * TSEQ + t] * EMB + d];
        v = s * (1.f / 32.f);
    } else {
        v = vg[b * EMB + (d - EMB)];
    }
    xm16[i] = (__bf16)v;
}

// ---------------- generic NT GEMM: C[M,N] (+=) A_bf16[M,K] @ B_f32[N,K]^T (+bias) ----------------
constexpr int KP = 40;   // 32 + 8 pad (bf16 elems) -> 80B row stride, conflict-light

template <int BM, int BN, bool BIAS, bool ACCUM>
__global__ __launch_bounds__(256) void gemm_nt(const __bf16* __restrict__ A,
                                               const float* __restrict__ B,
                                               const float* __restrict__ bias,
                                               float* __restrict__ C,
                                               int M, int N, int Kd) {
    constexpr int WSUBM = BM / 2, WSUBN = BN / 2;
    constexpr int WM = WSUBM / 16, WN = WSUBN / 16;
    __shared__ __bf16 Al[BM * KP];
    __shared__ __bf16 Bl[BN * KP];
    int tid = threadIdx.x;
    int lane = tid & 63, wv = tid >> 6;
    int wm = wv >> 1, wn = wv & 1;
    int ln = lane & 15, qk = lane >> 4;
    int m0 = blockIdx.x * BM, n0 = blockIdx.y * BN;

    floatx4 zf = {0.f, 0.f, 0.f, 0.f};
    floatx4 acc[WM][WN];
#pragma unroll
    for (int i = 0; i < WM; i++)
#pragma unroll
        for (int j = 0; j < WN; j++) acc[i][j] = zf;

    for (int k0 = 0; k0 < Kd; k0 += 32) {
        __syncthreads();
        // stage A (bf16)
        for (int c = tid; c < BM * 4; c += 256) {
            int row = c >> 2, part = c & 3;
            int gr = m0 + row;
            bf16x8 v = (gr < M) ? *(const bf16x8*)(A + (size_t)gr * Kd + k0 + part * 8) : zero8();
            *(bf16x8*)&Al[row * KP + part * 8] = v;
        }
        // stage B (fp32 -> bf16)
        for (int c = tid; c < BN * 8; c += 256) {
            int row = c >> 3, part = c & 7;
            int gr = n0 + row;
            bf16x4 v;
            if (gr < N) {
                float4 u = *(const float4*)(B + (size_t)gr * Kd + k0 + part * 4);
                v[0] = (__bf16)u.x; v[1] = (__bf16)u.y; v[2] = (__bf16)u.z; v[3] = (__bf16)u.w;
            } else {
                v[0] = v[1] = v[2] = v[3] = (__bf16)0.f;
            }
            *(bf16x4*)&Bl[row * KP + part * 4] = v;
        }
        __syncthreads();
        bf16x8 af[WM], bfv[WN];
#pragma unroll
        for (int i = 0; i < WM; i++)
            af[i] = *(const bf16x8*)&Al[(wm * WSUBM + i * 16 + ln) * KP + qk * 8];
#pragma unroll
        for (int j = 0; j < WN; j++)
            bfv[j] = *(const bf16x8*)&Bl[(wn * WSUBN + j * 16 + ln) * KP + qk * 8];
#pragma unroll
        for (int i = 0; i < WM; i++)
#pragma unroll
            for (int j = 0; j < WN; j++)
                acc[i][j] = __builtin_amdgcn_mfma_f32_16x16x32_bf16(af[i], bfv[j], acc[i][j], 0, 0, 0);
    }
    // epilogue: D row = qk*4+r (A's m), col = ln (B's n)  [m89-verified layout]
#pragma unroll
    for (int i = 0; i < WM; i++) {
#pragma unroll
        for (int j = 0; j < WN; j++) {
            int gcol = n0 + wn * WSUBN + j * 16 + ln;
            if (gcol < N) {
#pragma unroll
                for (int r = 0; r < 4; r++) {
                    int grow = m0 + wm * WSUBM + i * 16 + qk * 4 + r;
                    if (grow < M) {
                        float v = acc[i][j][r];
                        if (BIAS) v += bias[gcol];
                        size_t idx = (size_t)grow * N + gcol;
                        if (ACCUM) v += C[idx];
                        C[idx] = v;
                    }
                }
            }
        }
    }
}

// ---------------- persistent LSTM: 48 blocks, 192 waves, 1 grid-barrier/step ----------------
__global__ __launch_bounds__(256) void k_lstm(const float* __restrict__ xg,
                                              const float* __restrict__ Whh,
                                              float* __restrict__ hiddens,
                                              float* __restrict__ cells,
                                              __bf16* __restrict__ hid16,
                                              __bf16* __restrict__ hprev16,
                                              __bf16* __restrict__ hb0,
                                              __bf16* __restrict__ hb1,
                                              unsigned* __restrict__ bar) {
    __shared__ float wg[4][16][17];
    int tid = threadIdx.x, lane = tid & 63, wv = tid >> 6;
    int W = blockIdx.x * 4 + wv;      // 0..191
    int c4 = W * 4;                   // 4 owned h-columns
    int ln = lane & 15, qk = lane >> 4;
    // MFMA B-operand: lane ln -> gate column
    int gate = ln >> 2, gjj = ln & 3;
    int gcol = gate * HID + c4 + gjj;
    // elementwise ownership: (batch eb, column ej)
    int eb = ln, jj = qk, ej = c4 + jj;

    // preload this lane's Whh slice as bf16 fragments (fp32 -> bf16)
    bf16x8 bfr[24];
    const float* wrow = Whh + (size_t)gcol * HID + qk * 8;
#pragma unroll
    for (int ki = 0; ki < 24; ki++) {
        float4 u0 = *(const float4*)(wrow + ki * 32);
        float4 u1 = *(const float4*)(wrow + ki * 32 + 4);
        bf16x8 f;
        f[0] = (__bf16)u0.x; f[1] = (__bf16)u0.y; f[2] = (__bf16)u0.z; f[3] = (__bf16)u0.w;
        f[4] = (__bf16)u1.x; f[5] = (__bf16)u1.y; f[6] = (__bf16)u1.z; f[7] = (__bf16)u1.w;
        bfr[ki] = f;
    }

    // init h0 = 0 (own columns), hprev row t=0 = 0
    float cst = 0.f;
    hb0[eb * HID + ej] = (__bf16)0.f;
    hprev16[((size_t)eb * TSEQ + 0) * HID + ej] = (__bf16)0.f;
    grid_barrier(bar, 32, NB_LSTM);

    __bf16* hcur = hb0;
    __bf16* hnxt = hb1;
    floatx4 zf = {0.f, 0.f, 0.f, 0.f};
#pragma unroll 1
    for (int t = 0; t < TSEQ; t++) {
        floatx4 acc = zf;
        const __bf16* abase = hcur + ln * HID + qk * 8;
#pragma unroll
        for (int ki = 0; ki < 24; ki++) {
            bf16x8 a = *(const bf16x8*)(abase + ki * 32);
            acc = __builtin_amdgcn_mfma_f32_16x16x32_bf16(a, bfr[ki], acc, 0, 0, 0);
        }
        // acc[r] = gates[b=qk*4+r][gcol]; add xg, park in LDS for i/f/g/o gather
#pragma unroll
        for (int r = 0; r < 4; r++) {
            int bb = qk * 4 + r;
            wg[wv][bb][ln] = acc[r] + xg[((size_t)bb * TSEQ + t) * G4 + gcol];
        }
        __syncthreads();
        float iv = wg[wv][eb][0 + jj];
        float fv = wg[wv][eb][4 + jj];
        float gv = wg[wv][eb][8 + jj];
        float ov = wg[wv][eb][12 + jj];
        float ig = sigm_f(iv), fg = sigm_f(fv), gg = tanh_f(gv), og = sigm_f(ov);
        cst = fg * cst + ig * gg;
        float h = og * tanh_f(cst);
        size_t bt = (size_t)eb * TSEQ + t;
        hiddens[bt * HID + ej] = h;
        cells[bt * HID + ej] = cst;
        __bf16 hb_ = (__bf16)h;
        hid16[bt * HID + ej] = hb_;
        if (t < TSEQ - 1) hprev16[(bt + 1) * HID + ej] = hb_;
        hnxt[eb * HID + ej] = hb_;
        grid_barrier(bar, t, NB_LSTM);
        __bf16* tmp = hcur; hcur = hnxt; hnxt = tmp;
    }
}

// ---------------- switch: e=tanh(epre+bias2), sw=sigmoid(e.sw_w), swout=sw*V ----------------
__global__ __launch_bounds__(256) void k_switch(const float* __restrict__ epre,
                                                const float* __restrict__ bias2,
                                                const float* __restrict__ sww,
                                                const float* __restrict__ Vin,
                                                float* __restrict__ swout,
                                                __bf16* __restrict__ swout16) {
    int row = blockIdx.x;       // 0..783 (b*49+k)
    int b = row / KREG;
    int tid = threadIdx.x;
    float s = 0.f;
#pragma unroll
    for (int u = 0; u < 3; u++) {
        int h = tid + u * 256;
        float e = tanh_f(epre[(size_t)row * HID + h] + bias2[b * HID + h]);
        s += e * sww[h];
    }
    for (int off = 32; off; off >>= 1) s += __shfl_xor(s, off);
    __shared__ float r4[4];
    __shared__ float swsh;
    if ((tid & 63) == 0) r4[tid >> 6] = s;
    __syncthreads();
    if (tid == 0) swsh = sigm_f(r4[0] + r4[1] + r4[2] + r4[3]);
    __syncthreads();
    float sw = swsh;
#pragma unroll
    for (int u = 0; u < 3; u++) {
        int h = tid + u * 256;
        float so = sw * Vin[(size_t)row * HID + h];
        swout[(size_t)row * HID + h] = so;
        swout16[(size_t)row * HID + h] = (__bf16)so;
    }
}

// ---------------- sentinel = sigmoid(gpre) * tanh(cells) ----------------
__global__ __launch_bounds__(256) void k_sentinel(const float* __restrict__ gpre,
                                                  const float* __restrict__ cells,
                                                  float* __restrict__ sent,
                                                  __bf16* __restrict__ sent16) {
    size_t i = (size_t)blockIdx.x * 256 + threadIdx.x;
    if (i >= (size_t)BT * HID) return;
    float g = sigm_f(gpre[i]);
    float sv = g * tanh_f(cells[i]);
    sent[i] = sv;
    sent16[i] = (__bf16)sv;
}

// ---------------- attention: z/zs, softmax(50), c_t, c_hat, chs_b16, alpha/beta out ----------------
__global__ __launch_bounds__(256) void k_attn(const float* __restrict__ cv,
                                              const float* __restrict__ hg,
                                              const float* __restrict__ spre,
                                              const float* __restrict__ atw,
                                              const float* __restrict__ swout,
                                              const float* __restrict__ sent,
                                              const float* __restrict__ hiddens,
                                              float* __restrict__ alpha_out,
                                              float* __restrict__ beta_out,
                                              __bf16* __restrict__ chs16) {
    int bt = blockIdx.x;
    int b = bt >> 5;
    int tid = threadIdx.x, lane = tid & 63, wv = tid >> 6;
    __shared__ float zl[64];
    __shared__ float al[64];
    const float* hgr = hg + (size_t)bt * HID;
    for (int r = wv; r < KREG + 1; r += 4) {
        const float* src = (r < KREG) ? (cv + ((size_t)b * KREG + r) * HID) : (spre + (size_t)bt * HID);
        float s = 0.f;
#pragma unroll
        for (int u = 0; u < 12; u++) {
            int h = lane + u * 64;
            s += tanh_f(src[h] + hgr[h]) * atw[h];
        }
        for (int off = 32; off; off >>= 1) s += __shfl_xor(s, off);
        if (lane == 0) zl[r] = s;
    }
    __syncthreads();
    if (wv == 0) {
        float z = (lane < KREG + 1) ? zl[lane] : -3.4e38f;
        float m = z;
        for (int off = 32; off; off >>= 1) m = fmaxf(m, __shfl_xor(m, off));
        float e = (lane < KREG + 1) ? __expf(z - m) : 0.f;
        float su = e;
        for (int off = 32; off; off >>= 1) su += __shfl_xor(su, off);
        float a = e / su;
        if (lane < KREG + 1) al[lane] = a;
        if (lane < KREG) alpha_out[(size_t)bt * KREG + lane] = a;
        if (lane == KREG) beta_out[bt] = a;
    }
    __syncthreads();
    float beta = al[KREG];
#pragma unroll
    for (int u = 0; u < 3; u++) {
        int h = tid + u * 256;
        float ct = 0.f;
        for (int k = 0; k < KREG; k++) ct += al[k] * swout[((size_t)b * KREG + k) * HID + h];
        float chat = beta * sent[(size_t)bt * HID + h] + (1.f - beta) * ct;
        chs16[(size_t)bt * HID + h] = (__bf16)(chat + hiddens[(size_t)bt * HID + h]);
    }
}

// ---------------- host launcher ----------------
extern "C" void kernel_launch(void* const* d_in, const int* in_sizes, int n_in,
                              void* d_out, int out_size, void* d_ws, size_t ws_size,
                              hipStream_t stream) {
    (void)in_sizes; (void)n_in; (void)out_size; (void)ws_size;
    const float* Vin  = (const float*)d_in[0];
    const float* vg   = (const float*)d_in[1];
    const int*   cap  = (const int*)d_in[2];
    const float* embW = (const float*)d_in[3];
    const float* Wih  = (const float*)d_in[4];
    const float* Whh  = (const float*)d_in[5];
    const float* lb   = (const float*)d_in[6];
    const float* sWx  = (const float*)d_in[7];
    const float* sWh  = (const float*)d_in[8];
    const float* swWg = (const float*)d_in[9];
    const float* swWh = (const float*)d_in[10];
    const float* swWx = (const float*)d_in[11];
    const float* sww  = (const float*)d_in[12];
    const float* atWv = (const float*)d_in[13];
    const float* atWg = (const float*)d_in[14];
    const float* atWs = (const float*)d_in[15];
    const float* atw  = (const float*)d_in[16];
    const float* mlpW = (const float*)d_in[17];
    const float* mlpb = (const float*)d_in[18];

    float* scores    = (float*)d_out;
    float* alpha_out = scores + (size_t)BT * NVOC;
    float* beta_out  = alpha_out + (size_t)BT * KREG;

    char* p = (char*)d_ws;
    auto alloc = [&](size_t bytes) {
        void* r = (void*)p;
        p += (bytes + 255) & ~(size_t)255;
        return r;
    };
    __bf16* x16     = (__bf16*)alloc((size_t)BT * TWOE * 2);
    __bf16* V16     = (__bf16*)alloc((size_t)BATCH * KREG * EMB * 2);
    __bf16* vg16    = (__bf16*)alloc((size_t)BATCH * HID * 2);
    __bf16* xm16    = (__bf16*)alloc((size_t)BATCH * TWOE * 2);
    float*  xg      = (float*)alloc((size_t)BT * G4 * 4);
    float*  bias2   = (float*)alloc((size_t)BATCH * HID * 4);
    float*  hidd    = (float*)alloc((size_t)BT * HID * 4);
    float*  cells   = (float*)alloc((size_t)BT * HID * 4);
    __bf16* hid16   = (__bf16*)alloc((size_t)BT * HID * 2);
    __bf16* hprev16 = (__bf16*)alloc((size_t)BT * HID * 2);
    __bf16* hb0     = (__bf16*)alloc((size_t)BATCH * HID * 2);
    __bf16* hb1     = (__bf16*)alloc((size_t)BATCH * HID * 2);
    unsigned* bar   = (unsigned*)alloc(64 * 4);
    float*  gpre    = (float*)alloc((size_t)BT * HID * 4);
    float*  epre    = (float*)alloc((size_t)BATCH * KREG * HID * 4);
    float*  swout   = (float*)alloc((size_t)BATCH * KREG * HID * 4);
    __bf16* swout16 = (__bf16*)alloc((size_t)BATCH * KREG * HID * 2);
    float*  sent    = (float*)alloc((size_t)BT * HID * 4);
    __bf16* sent16  = (__bf16*)alloc((size_t)BT * HID * 2);
    float*  cvb     = (float*)alloc((size_t)BATCH * KREG * HID * 4);
    float*  hgb     = (float*)alloc((size_t)BT * HID * 4);
    float*  spre    = (float*)alloc((size_t)BT * HID * 4);
    __bf16* chs16   = (__bf16*)alloc((size_t)BT * HID * 2);

    const int TOT_INIT = BT * TWOE + BATCH * KREG * EMB + BATCH * HID + 64;
    k_init<<<(TOT_INIT + 255) / 256, 256, 0, stream>>>(cap, embW, vg, Vin, x16, V16, vg16, bar);
    k_xmean<<<(BATCH * TWOE + 255) / 256, 256, 0, stream>>>(cap, embW, vg, xm16);

    // xg = x @ Wih^T + lstm_b       (512 x 3072, K=1536)
    gemm_nt<128, 128, true, false><<<dim3(4, 24), 256, 0, stream>>>(x16, Wih, lb, xg, BT, G4, TWOE);
    // bias2 = v_g @ sw_Wh^T + xmean @ sw_Wx^T   (16 x 768)
    gemm_nt<64, 64, false, false><<<dim3(1, 12), 256, 0, stream>>>(vg16, swWh, nullptr, bias2, BATCH, HID, HID);
    gemm_nt<64, 64, false, true><<<dim3(1, 12), 256, 0, stream>>>(xm16, swWx, nullptr, bias2, BATCH, HID, TWOE);
    // LSTM (persistent, 48 blocks)
    k_lstm<<<NB_LSTM, 256, 0, stream>>>(xg, Whh, hidd, cells, hid16, hprev16, hb0, hb1, bar);
    // sentinel gate pre: gpre = x @ sent_Wx^T + h_prev @ sent_Wh^T
    gemm_nt<64, 64, false, false><<<dim3(8, 12), 256, 0, stream>>>(x16, sWx, nullptr, gpre, BT, HID, TWOE);
    gemm_nt<64, 64, false, true><<<dim3(8, 12), 256, 0, stream>>>(hprev16, sWh, nullptr, gpre, BT, HID, HID);
    // epre = V @ sw_Wg^T            (784 x 768)
    gemm_nt<64, 64, false, false><<<dim3(13, 12), 256, 0, stream>>>(V16, swWg, nullptr, epre, BATCH * KREG, HID, HID);
    k_switch<<<BATCH * KREG, 256, 0, stream>>>(epre, bias2, sww, Vin, swout, swout16);
    k_sentinel<<<(BT * HID + 255) / 256, 256, 0, stream>>>(gpre, cells, sent, sent16);
    // cv / hg / spre
    gemm_nt<64, 64, false, false><<<dim3(13, 12), 256, 0, stream>>>(swout16, atWv, nullptr, cvb, BATCH * KREG, HID, HID);
    gemm_nt<64, 64, false, false><<<dim3(8, 12), 256, 0, stream>>>(hid16, atWg, nullptr, hgb, BT, HID, HID);
    gemm_nt<64, 64, false, false><<<dim3(8, 12), 256, 0, stream>>>(sent16, atWs, nullptr, spre, BT, HID, HID);
    k_attn<<<BT, 256, 0, stream>>>(cvb, hgb, spre, atw, swout, sent, hidd, alpha_out, beta_out, chs16);
    // scores = chs @ mlp_W^T + mlp_b   (512 x 50257, K=768); M-tile fastest for LLC reuse of mlp_W
    gemm_nt<128, 128, true, false><<<dim3(4, 393), 256, 0, stream>>>(chs16, mlpW, mlpb, scores, BT, NVOC, HID);
}

// Round 2
// 1254.850 us; speedup vs baseline: 1.2712x; 1.2712x over previous
//
#include <hip/hip_runtime.h>

// ---------------- problem constants ----------------
constexpr int BATCH = 16;
constexpr int TSEQ  = 32;
constexpr int BT    = BATCH * TSEQ;      // 512
constexpr int HID   = 768;
constexpr int EMB   = 768;
constexpr int TWOE  = 1536;
constexpr int G4    = 3072;              // 4*H
constexpr int KREG  = 49;
constexpr int NVOC  = 50257;
constexpr int NB_LSTM = 48;

typedef __bf16 bf16x8 __attribute__((ext_vector_type(8)));
typedef __bf16 bf16x4 __attribute__((ext_vector_type(4)));
typedef float  floatx4 __attribute__((ext_vector_type(4)));

__device__ __forceinline__ float sigm_f(float x) { return 1.f / (1.f + __expf(-x)); }
__device__ __forceinline__ float tanh_f(float x) {
    float e = __expf(2.f * x);
    return 1.f - 2.f / (e + 1.f);     // stable for +/- inf
}
__device__ __forceinline__ bf16x8 zero8() {
    bf16x8 v;
#pragma unroll
    for (int i = 0; i < 8; i++) v[i] = (__bf16)0.f;
    return v;
}

// ---------------- init: x_b16 build, V_b16, vg_b16, xmean ----------------
__global__ __launch_bounds__(256) void k_init(const int* __restrict__ cap,
                                              const float* __restrict__ embW,
                                              const float* __restrict__ vg,
                                              const float* __restrict__ Vin,
                                              __bf16* __restrict__ x16,
                                              __bf16* __restrict__ V16,
                                              __bf16* __restrict__ vg16,
                                              __bf16* __restrict__ xm16) {
    const int NX = BT * TWOE;            // 786432
    const int NV = BATCH * KREG * EMB;   // 602112
    const int NG = BATCH * HID;          // 12288
    const int NM = BATCH * TWOE;         // 24576
    int i = blockIdx.x * 256 + threadIdx.x;
    if (i < NX) {
        int bt = i / TWOE, d = i - bt * TWOE;
        float v;
        if (d < EMB) {
            int tok = cap[bt];
            v = embW[(size_t)tok * EMB + d];
        } else {
            int b = bt >> 5;
            v = vg[b * EMB + (d - EMB)];
        }
        x16[i] = (__bf16)v;
    } else if (i < NX + NV) {
        int j = i - NX;
        V16[j] = (__bf16)Vin[j];
    } else if (i < NX + NV + NG) {
        int j = i - NX - NV;
        vg16[j] = (__bf16)vg[j];
    } else if (i < NX + NV + NG + NM) {
        int j = i - NX - NV - NG;
        int b = j / TWOE, d = j - b * TWOE;
        float v;
        if (d < EMB) {
            float s = 0.f;
            for (int t = 0; t < TSEQ; t++) s += embW[(size_t)cap[b * TSEQ + t] * EMB + d];
            v = s * (1.f / 32.f);
        } else {
            v = vg[b * EMB + (d - EMB)];
        }
        xm16[j] = (__bf16)v;
    }
}

// ---------------- fp32 -> bf16 streaming convert ----------------
__global__ __launch_bounds__(256) void k_cvt(const float* __restrict__ src,
                                             __bf16* __restrict__ dst, int n8) {
    int i = blockIdx.x * 256 + threadIdx.x;
    int stride = gridDim.x * 256;
    for (; i < n8; i += stride) {
        float4 u0 = *(const float4*)(src + (size_t)i * 8);
        float4 u1 = *(const float4*)(src + (size_t)i * 8 + 4);
        bf16x8 f;
        f[0] = (__bf16)u0.x; f[1] = (__bf16)u0.y; f[2] = (__bf16)u0.z; f[3] = (__bf16)u0.w;
        f[4] = (__bf16)u1.x; f[5] = (__bf16)u1.y; f[6] = (__bf16)u1.z; f[7] = (__bf16)u1.w;
        *(bf16x8*)(dst + (size_t)i * 8) = f;
    }
}

// ---------------- generic NT GEMM ----------------
// C[M,N] = A_bf16[M,K] @ B[N,K]^T (+bias). B fp32 (converted inline) or bf16.
// ATOMIC: atomicAdd into pre-zeroed C (enables split-K via gridDim.z).
// PERM:   store row' = (row%32)*16 + row/32  (bt -> t-major for the LSTM).
constexpr int KP = 40;   // 32 + 8 pad (bf16 elems) -> 80B row stride, conflict-light

template <int BM, int BN, bool BIAS, bool BF16B, bool ATOMIC, bool PERM>
__global__ __launch_bounds__(256) void gemm_nt(const __bf16* __restrict__ A,
                                               const void* __restrict__ Bv,
                                               const float* __restrict__ bias,
                                               float* __restrict__ C,
                                               int M, int N, int Kd) {
    constexpr int WSUBM = BM / 2, WSUBN = BN / 2;
    constexpr int WM = WSUBM / 16, WN = WSUBN / 16;
    __shared__ __bf16 Al[BM * KP];
    __shared__ __bf16 Bl[BN * KP];
    int tid = threadIdx.x;
    int lane = tid & 63, wv = tid >> 6;
    int wm = wv >> 1, wn = wv & 1;
    int ln = lane & 15, qk = lane >> 4;
    int m0 = blockIdx.x * BM, n0 = blockIdx.y * BN;
    int kc = Kd / gridDim.z;
    int kbeg = blockIdx.z * kc;

    floatx4 zf = {0.f, 0.f, 0.f, 0.f};
    floatx4 acc[WM][WN];
#pragma unroll
    for (int i = 0; i < WM; i++)
#pragma unroll
        for (int j = 0; j < WN; j++) acc[i][j] = zf;

    for (int k0 = kbeg; k0 < kbeg + kc; k0 += 32) {
        __syncthreads();
        // stage A (bf16)
        for (int c = tid; c < BM * 4; c += 256) {
            int row = c >> 2, part = c & 3;
            int gr = m0 + row;
            bf16x8 v = (gr < M) ? *(const bf16x8*)(A + (size_t)gr * Kd + k0 + part * 8) : zero8();
            *(bf16x8*)&Al[row * KP + part * 8] = v;
        }
        // stage B
        if (BF16B) {
            const __bf16* B16 = (const __bf16*)Bv;
            for (int c = tid; c < BN * 4; c += 256) {
                int row = c >> 2, part = c & 3;
                int gr = n0 + row;
                bf16x8 v = (gr < N) ? *(const bf16x8*)(B16 + (size_t)gr * Kd + k0 + part * 8) : zero8();
                *(bf16x8*)&Bl[row * KP + part * 8] = v;
            }
        } else {
            const float* B = (const float*)Bv;
            for (int c = tid; c < BN * 8; c += 256) {
                int row = c >> 3, part = c & 7;
                int gr = n0 + row;
                bf16x4 v;
                if (gr < N) {
                    float4 u = *(const float4*)(B + (size_t)gr * Kd + k0 + part * 4);
                    v[0] = (__bf16)u.x; v[1] = (__bf16)u.y; v[2] = (__bf16)u.z; v[3] = (__bf16)u.w;
                } else {
                    v[0] = v[1] = v[2] = v[3] = (__bf16)0.f;
                }
                *(bf16x4*)&Bl[row * KP + part * 4] = v;
            }
        }
        __syncthreads();
        bf16x8 af[WM], bfv[WN];
#pragma unroll
        for (int i = 0; i < WM; i++)
            af[i] = *(const bf16x8*)&Al[(wm * WSUBM + i * 16 + ln) * KP + qk * 8];
#pragma unroll
        for (int j = 0; j < WN; j++)
            bfv[j] = *(const bf16x8*)&Bl[(wn * WSUBN + j * 16 + ln) * KP + qk * 8];
#pragma unroll
        for (int i = 0; i < WM; i++)
#pragma unroll
            for (int j = 0; j < WN; j++)
                acc[i][j] = __builtin_amdgcn_mfma_f32_16x16x32_bf16(af[i], bfv[j], acc[i][j], 0, 0, 0);
    }
    // epilogue: D row = qk*4+r (A's m), col = ln (B's n)  [m89-verified layout]
#pragma unroll
    for (int i = 0; i < WM; i++) {
#pragma unroll
        for (int j = 0; j < WN; j++) {
            int gcol = n0 + wn * WSUBN + j * 16 + ln;
            if (gcol < N) {
#pragma unroll
                for (int r = 0; r < 4; r++) {
                    int grow = m0 + wm * WSUBM + i * 16 + qk * 4 + r;
                    if (grow < M) {
                        float v = acc[i][j][r];
                        if (BIAS) v += bias[gcol];
                        int orow = PERM ? ((grow & 31) * 16 + (grow >> 5)) : grow;
                        size_t idx = (size_t)orow * N + gcol;
                        if (ATOMIC) atomicAdd(&C[idx], v);
                        else C[idx] = v;
                    }
                }
            }
        }
    }
}

// ---------------- persistent LSTM: 48 blocks, flag-tree grid barrier ----------------
// flags: one cacheline (32 uints) per block; value = completed-step count (monotone).
__global__ __launch_bounds__(256) void k_lstm(const float* __restrict__ xgp,
                                              const float* __restrict__ Whh,
                                              float* __restrict__ hiddens,
                                              float* __restrict__ cells,
                                              __bf16* __restrict__ hid16,
                                              __bf16* __restrict__ hprev16,
                                              __bf16* __restrict__ hb0,
                                              __bf16* __restrict__ hb1,
                                              unsigned* __restrict__ flags) {
    __shared__ float wg[4][16][17];
    int tid = threadIdx.x, lane = tid & 63, wv = tid >> 6;
    int bid = blockIdx.x;
    int W = bid * 4 + wv;             // 0..191
    int c4 = W * 4;                   // 4 owned h-columns
    int ln = lane & 15, qk = lane >> 4;
    // MFMA B-operand: lane ln -> gate column
    int gate = ln >> 2, gjj = ln & 3;
    int gcol = gate * HID + c4 + gjj;
    // elementwise ownership: (batch eb, column ej)
    int eb = ln, jj = qk, ej = c4 + jj;

    // preload this lane's Whh slice as bf16 fragments (fp32 -> bf16)
    bf16x8 bfr[24];
    const float* wrow = Whh + (size_t)gcol * HID + qk * 8;
#pragma unroll
    for (int ki = 0; ki < 24; ki++) {
        float4 u0 = *(const float4*)(wrow + ki * 32);
        float4 u1 = *(const float4*)(wrow + ki * 32 + 4);
        bf16x8 f;
        f[0] = (__bf16)u0.x; f[1] = (__bf16)u0.y; f[2] = (__bf16)u0.z; f[3] = (__bf16)u0.w;
        f[4] = (__bf16)u1.x; f[5] = (__bf16)u1.y; f[6] = (__bf16)u1.z; f[7] = (__bf16)u1.w;
        bfr[ki] = f;
    }

    // h0 (hb0) and hprev16 row t=0 pre-zeroed by host memset; flags pre-zeroed.
    float cst = 0.f;
    __bf16* hcur = hb0;
    __bf16* hnxt = hb1;
    floatx4 zf = {0.f, 0.f, 0.f, 0.f};
#pragma unroll 1
    for (int t = 0; t < TSEQ; t++) {
        // prefetch xg for this step (t-major layout: row = t*16 + b)
        float xv[4];
#pragma unroll
        for (int r = 0; r < 4; r++) {
            int bb = qk * 4 + r;
            xv[r] = xgp[(size_t)(t * 16 + bb) * G4 + gcol];
        }
        // gates = h_{t-1} @ Whh^T : two independent MFMA chains
        floatx4 acc0 = zf, acc1 = zf;
        const __bf16* abase = hcur + ln * HID + qk * 8;
#pragma unroll
        for (int ki = 0; ki < 24; ki += 2) {
            bf16x8 a0 = *(const bf16x8*)(abase + ki * 32);
            bf16x8 a1 = *(const bf16x8*)(abase + ki * 32 + 32);
            acc0 = __builtin_amdgcn_mfma_f32_16x16x32_bf16(a0, bfr[ki], acc0, 0, 0, 0);
            acc1 = __builtin_amdgcn_mfma_f32_16x16x32_bf16(a1, bfr[ki + 1], acc1, 0, 0, 0);
        }
#pragma unroll
        for (int r = 0; r < 4; r++) {
            int bb = qk * 4 + r;
            wg[wv][bb][ln] = acc0[r] + acc1[r] + xv[r];
        }
        __syncthreads();
        float iv = wg[wv][eb][0 + jj];
        float fv = wg[wv][eb][4 + jj];
        float gv = wg[wv][eb][8 + jj];
        float ov = wg[wv][eb][12 + jj];
        float ig = sigm_f(iv), fg = sigm_f(fv), gg = tanh_f(gv), og = sigm_f(ov);
        cst = fg * cst + ig * gg;
        float h = og * tanh_f(cst);
        size_t bt = (size_t)eb * TSEQ + t;
        hiddens[bt * HID + ej] = h;
        cells[bt * HID + ej] = cst;
        __bf16 hb_ = (__bf16)h;
        hid16[bt * HID + ej] = hb_;
        if (t < TSEQ - 1) hprev16[(bt + 1) * HID + ej] = hb_;
        hnxt[eb * HID + ej] = hb_;
        if (t < TSEQ - 1) {
            // grid barrier: publish own flag, poll all 48 in parallel (1 LLC round-trip)
            unsigned target = t + 1;
            __threadfence();
            __syncthreads();
            if (tid == 0)
                __hip_atomic_store(&flags[bid * 32], target, __ATOMIC_RELEASE, __HIP_MEMORY_SCOPE_AGENT);
            if (wv == 0 && lane < NB_LSTM) {
                while (__hip_atomic_load(&flags[lane * 32], __ATOMIC_ACQUIRE, __HIP_MEMORY_SCOPE_AGENT) < target) {
                    __builtin_amdgcn_s_sleep(1);
                }
            }
            __syncthreads();
            __threadfence();
        }
        __bf16* tmp = hcur; hcur = hnxt; hnxt = tmp;
    }
}

// ---------------- switch: e=tanh(epre+bias2), sw=sigmoid(e.sw_w), swout=sw*V ----------------
__global__ __launch_bounds__(256) void k_switch(const float* __restrict__ epre,
                                                const float* __restrict__ bias2,
                                                const float* __restrict__ sww,
                                                const float* __restrict__ Vin,
                                                float* __restrict__ swout,
                                                __bf16* __restrict__ swout16) {
    int row = blockIdx.x;       // 0..783 (b*49+k)
    int b = row / KREG;
    int tid = threadIdx.x;
    float s = 0.f;
#pragma unroll
    for (int u = 0; u < 3; u++) {
        int h = tid + u * 256;
        float e = tanh_f(epre[(size_t)row * HID + h] + bias2[b * HID + h]);
        s += e * sww[h];
    }
    for (int off = 32; off; off >>= 1) s += __shfl_xor(s, off);
    __shared__ float r4[4];
    __shared__ float swsh;
    if ((tid & 63) == 0) r4[tid >> 6] = s;
    __syncthreads();
    if (tid == 0) swsh = sigm_f(r4[0] + r4[1] + r4[2] + r4[3]);
    __syncthreads();
    float sw = swsh;
#pragma unroll
    for (int u = 0; u < 3; u++) {
        int h = tid + u * 256;
        float so = sw * Vin[(size_t)row * HID + h];
        swout[(size_t)row * HID + h] = so;
        swout16[(size_t)row * HID + h] = (__bf16)so;
    }
}

// ---------------- sentinel = sigmoid(gpre) * tanh(cells) ----------------
__global__ __launch_bounds__(256) void k_sentinel(const float* __restrict__ gpre,
                                                  const float* __restrict__ cells,
                                                  float* __restrict__ sent,
                                                  __bf16* __restrict__ sent16) {
    size_t i = (size_t)blockIdx.x * 256 + threadIdx.x;
    if (i >= (size_t)BT * HID) return;
    float g = sigm_f(gpre[i]);
    float sv = g * tanh_f(cells[i]);
    sent[i] = sv;
    sent16[i] = (__bf16)sv;
}

// ---------------- attention: z/zs, softmax(50), c_t, c_hat, chs_b16 ----------------
__global__ __launch_bounds__(256) void k_attn(const float* __restrict__ cv,
                                              const float* __restrict__ hg,
                                              const float* __restrict__ spre,
                                              const float* __restrict__ atw,
                                              const float* __restrict__ swout,
                                              const float* __restrict__ sent,
                                              const float* __restrict__ hiddens,
                                              float* __restrict__ alpha_out,
                                              float* __restrict__ beta_out,
                                              __bf16* __restrict__ chs16) {
    int bt = blockIdx.x;
    int b = bt >> 5;
    int tid = threadIdx.x, lane = tid & 63, wv = tid >> 6;
    __shared__ float zl[64];
    __shared__ float al[64];
    const float* hgr = hg + (size_t)bt * HID;
    for (int r = wv; r < KREG + 1; r += 4) {
        const float* src = (r < KREG) ? (cv + ((size_t)b * KREG + r) * HID) : (spre + (size_t)bt * HID);
        float s = 0.f;
#pragma unroll
        for (int u = 0; u < 12; u++) {
            int h = lane + u * 64;
            s += tanh_f(src[h] + hgr[h]) * atw[h];
        }
        for (int off = 32; off; off >>= 1) s += __shfl_xor(s, off);
        if (lane == 0) zl[r] = s;
    }
    __syncthreads();
    if (wv == 0) {
        float z = (lane < KREG + 1) ? zl[lane] : -3.4e38f;
        float m = z;
        for (int off = 32; off; off >>= 1) m = fmaxf(m, __shfl_xor(m, off));
        float e = (lane < KREG + 1) ? __expf(z - m) : 0.f;
        float su = e;
        for (int off = 32; off; off >>= 1) su += __shfl_xor(su, off);
        float a = e / su;
        if (lane < KREG + 1) al[lane] = a;
        if (lane < KREG) alpha_out[(size_t)bt * KREG + lane] = a;
        if (lane == KREG) beta_out[bt] = a;
    }
    __syncthreads();
    float beta = al[KREG];
#pragma unroll
    for (int u = 0; u < 3; u++) {
        int h = tid + u * 256;
        float ct = 0.f;
        for (int k = 0; k < KREG; k++) ct += al[k] * swout[((size_t)b * KREG + k) * HID + h];
        float chat = beta * sent[(size_t)bt * HID + h] + (1.f - beta) * ct;
        chs16[(size_t)bt * HID + h] = (__bf16)(chat + hiddens[(size_t)bt * HID + h]);
    }
}

// ---------------- host launcher ----------------
extern "C" void kernel_launch(void* const* d_in, const int* in_sizes, int n_in,
                              void* d_out, int out_size, void* d_ws, size_t ws_size,
                              hipStream_t stream) {
    (void)in_sizes; (void)n_in; (void)out_size;
    const float* Vin  = (const float*)d_in[0];
    const float* vg   = (const float*)d_in[1];
    const int*   cap  = (const int*)d_in[2];
    const float* embW = (const float*)d_in[3];
    const float* Wih  = (const float*)d_in[4];
    const float* Whh  = (const float*)d_in[5];
    const float* lb   = (const float*)d_in[6];
    const float* sWx  = (const float*)d_in[7];
    const float* sWh  = (const float*)d_in[8];
    const float* swWg = (const float*)d_in[9];
    const float* swWh = (const float*)d_in[10];
    const float* swWx = (const float*)d_in[11];
    const float* sww  = (const float*)d_in[12];
    const float* atWv = (const float*)d_in[13];
    const float* atWg = (const float*)d_in[14];
    const float* atWs = (const float*)d_in[15];
    const float* atw  = (const float*)d_in[16];
    const float* mlpW = (const float*)d_in[17];
    const float* mlpb = (const float*)d_in[18];

    float* scores    = (float*)d_out;
    float* alpha_out = scores + (size_t)BT * NVOC;
    float* beta_out  = alpha_out + (size_t)BT * KREG;

    char* p = (char*)d_ws;
    auto alloc = [&](size_t bytes) {
        void* r = (void*)p;
        p += (bytes + 255) & ~(size_t)255;
        return r;
    };
    __bf16* x16     = (__bf16*)alloc((size_t)BT * TWOE * 2);
    __bf16* V16     = (__bf16*)alloc((size_t)BATCH * KREG * EMB * 2);
    __bf16* vg16    = (__bf16*)alloc((size_t)BATCH * HID * 2);
    __bf16* xm16    = (__bf16*)alloc((size_t)BATCH * TWOE * 2);
    float*  xg      = (float*)alloc((size_t)BT * G4 * 4);       // t-major [t][b][g]
    float*  hidd    = (float*)alloc((size_t)BT * HID * 4);
    float*  cells   = (float*)alloc((size_t)BT * HID * 4);
    __bf16* hid16   = (__bf16*)alloc((size_t)BT * HID * 2);
    __bf16* hb1     = (__bf16*)alloc((size_t)BATCH * HID * 2);
    float*  epre    = (float*)alloc((size_t)BATCH * KREG * HID * 4);
    float*  swout   = (float*)alloc((size_t)BATCH * KREG * HID * 4);
    __bf16* swout16 = (__bf16*)alloc((size_t)BATCH * KREG * HID * 2);
    float*  sent    = (float*)alloc((size_t)BT * HID * 4);
    __bf16* sent16  = (__bf16*)alloc((size_t)BT * HID * 2);
    float*  cvb     = (float*)alloc((size_t)BATCH * KREG * HID * 4);
    float*  hgb     = (float*)alloc((size_t)BT * HID * 4);
    float*  spre    = (float*)alloc((size_t)BT * HID * 4);
    __bf16* chs16   = (__bf16*)alloc((size_t)BT * HID * 2);
    // ---- zero-init group (single memset covers all of these) ----
    char*   zbase   = p;
    float*  gpre    = (float*)alloc((size_t)BT * HID * 4);
    float*  bias2   = (float*)alloc((size_t)BATCH * HID * 4);
    __bf16* hprev16 = (__bf16*)alloc((size_t)BT * HID * 2);
    __bf16* hb0     = (__bf16*)alloc((size_t)BATCH * HID * 2);
    unsigned* flags = (unsigned*)alloc(NB_LSTM * 32 * 4);
    size_t  zbytes  = (size_t)(p - zbase);
    // ---- optional bf16 weight copies ----
    __bf16* wih16   = (__bf16*)alloc((size_t)G4 * TWOE * 2);
    __bf16* mlp16   = (__bf16*)alloc((size_t)NVOC * HID * 2);
    bool use_cvt = ((size_t)(p - (char*)d_ws) <= ws_size);

    hipMemsetAsync(zbase, 0, zbytes, stream);
    k_init<<<(BT * TWOE + BATCH * KREG * EMB + BATCH * HID + BATCH * TWOE + 255) / 256, 256, 0, stream>>>(
        cap, embW, vg, Vin, x16, V16, vg16, xm16);
    if (use_cvt) {
        k_cvt<<<2304, 256, 0, stream>>>(Wih, wih16, G4 * TWOE / 8);
        k_cvt<<<4096, 256, 0, stream>>>(mlpW, mlp16, NVOC * HID / 8);
    }

    // xg[t][b][g] = (x @ Wih^T + lstm_b) permuted   (512 x 3072, K=1536)
    if (use_cvt)
        gemm_nt<128, 128, true, true, false, true><<<dim3(4, 24), 256, 0, stream>>>(x16, wih16, lb, xg, BT, G4, TWOE);
    else
        gemm_nt<128, 128, true, false, false, true><<<dim3(4, 24), 256, 0, stream>>>(x16, Wih, lb, xg, BT, G4, TWOE);
    // bias2 = v_g @ sw_Wh^T + xmean @ sw_Wx^T  (16 x 768), split-K atomic
    gemm_nt<64, 64, false, false, true, false><<<dim3(1, 12, 4), 256, 0, stream>>>(vg16, swWh, nullptr, bias2, BATCH, HID, HID);
    gemm_nt<64, 64, false, false, true, false><<<dim3(1, 12, 8), 256, 0, stream>>>(xm16, swWx, nullptr, bias2, BATCH, HID, TWOE);
    // gpre += x @ sent_Wx^T   (before LSTM; h-part added after)
    gemm_nt<64, 64, false, false, true, false><<<dim3(8, 12, 2), 256, 0, stream>>>(x16, sWx, nullptr, gpre, BT, HID, TWOE);
    // LSTM (persistent, 48 blocks, flag barrier)
    k_lstm<<<NB_LSTM, 256, 0, stream>>>(xg, Whh, hidd, cells, hid16, hprev16, hb0, hb1, flags);
    // gpre += h_prev @ sent_Wh^T
    gemm_nt<64, 64, false, false, true, false><<<dim3(8, 12, 2), 256, 0, stream>>>(hprev16, sWh, nullptr, gpre, BT, HID, HID);
    // epre = V @ sw_Wg^T            (784 x 768)
    gemm_nt<64, 64, false, false, false, false><<<dim3(13, 12), 256, 0, stream>>>(V16, swWg, nullptr, epre, BATCH * KREG, HID, HID);
    k_switch<<<BATCH * KREG, 256, 0, stream>>>(epre, bias2, sww, Vin, swout, swout16);
    k_sentinel<<<(BT * HID + 255) / 256, 256, 0, stream>>>(gpre, cells, sent, sent16);
    // cv / hg / spre
    gemm_nt<64, 64, false, false, false, false><<<dim3(13, 12), 256, 0, stream>>>(swout16, atWv, nullptr, cvb, BATCH * KREG, HID, HID);
    gemm_nt<64, 64, false, false, false, false><<<dim3(8, 12), 256, 0, stream>>>(hid16, atWg, nullptr, hgb, BT, HID, HID);
    gemm_nt<64, 64, false, false, false, false><<<dim3(8, 12), 256, 0, stream>>>(sent16, atWs, nullptr, spre, BT, HID, HID);
    k_attn<<<BT, 256, 0, stream>>>(cvb, hgb, spre, atw, swout, sent, hidd, alpha_out, beta_out, chs16);
    // scores = chs @ mlp_W^T + mlp_b   (512 x 50257, K=768)
    if (use_cvt)
        gemm_nt<128, 128, true, true, false, false><<<dim3(4, 393), 256, 0, stream>>>(chs16, mlp16, mlpb, scores, BT, NVOC, HID);
    else
        gemm_nt<128, 128, true, false, false, false><<<dim3(4, 393), 256, 0, stream>>>(chs16, mlpW, mlpb, scores, BT, NVOC, HID);
}